// Round 1
// baseline (685.525 us; speedup 1.0000x reference)
//
#include <hip/hip_runtime.h>

#define BB 4
#define CCH 64
#define LLEN 4096
#define TQ 64
#define TK 64
#define NTHREADS 256
#define QSCALE 0.125f
#define LDP 68   // padded leading dim (floats): 68*4B=272B, 16B-aligned, breaks bank conflicts

__global__ __launch_bounds__(NTHREADS) void attn_fused(
    const float* __restrict__ qg, const float* __restrict__ kg,
    const float* __restrict__ vg, const float* __restrict__ maskg,
    float* __restrict__ outp, float* __restrict__ attnT)
{
    __shared__ __align__(16) float qs[CCH * LDP];   // [c][lq]
    __shared__ __align__(16) float ks[TK * LDP];    // [c][lk]; reused as at[lk][lq] in phase B
    __shared__ __align__(16) float vs[TK * LDP];    // [lk][c]  (transposed V tile)
    __shared__ float lms[TK];                       // log(mask+1e-6) for tile
    __shared__ float mvs[TK];                       // mask values for tile

    const int tid = threadIdx.x;
    const int tx = tid & 15;        // lk subtile (4 cols each)
    const int ty = tid >> 4;        // lq subtile (4 rows each), 16 groups
    const int b   = blockIdx.x / (LLEN / TQ);
    const int lq0 = (blockIdx.x % (LLEN / TQ)) * TQ;

    // ---- stage Q tile once: qs[c][i] = q[b][c][lq0+i] (coalesced) ----
    for (int idx = tid; idx < CCH * TQ; idx += NTHREADS) {
        int c = idx >> 6, i = idx & 63;
        qs[c * LDP + i] = qg[((size_t)(b * CCH + c)) * LLEN + lq0 + i];
    }

    float mrow[4], srow[4];
#pragma unroll
    for (int r = 0; r < 4; ++r) { mrow[r] = -1e30f; srow[r] = 0.0f; }

    // ================= Phase A: row max & sum =================
    for (int lk0 = 0; lk0 < LLEN; lk0 += TK) {
        __syncthreads();
        for (int idx = tid; idx < CCH * TK; idx += NTHREADS) {
            int c = idx >> 6, j = idx & 63;
            ks[c * LDP + j] = kg[((size_t)(b * CCH + c)) * LLEN + lk0 + j];
        }
        if (tid < TK)
            lms[tid] = __logf(maskg[(size_t)b * LLEN + lk0 + tid] + 1e-6f);
        __syncthreads();

        // energy subtile e[r][cc] for rows lq0+ty*4+r, cols lk0+tx*4+cc
        float e[4][4];
#pragma unroll
        for (int r = 0; r < 4; ++r)
#pragma unroll
            for (int cc = 0; cc < 4; ++cc) e[r][cc] = 0.0f;

        for (int c = 0; c < CCH; ++c) {
            float4 a4 = *(const float4*)&qs[c * LDP + (ty << 2)];
            float4 b4 = *(const float4*)&ks[c * LDP + (tx << 2)];
            float av[4] = {a4.x, a4.y, a4.z, a4.w};
            float bv[4] = {b4.x, b4.y, b4.z, b4.w};
#pragma unroll
            for (int r = 0; r < 4; ++r)
#pragma unroll
                for (int cc = 0; cc < 4; ++cc) e[r][cc] += av[r] * bv[cc];
        }

#pragma unroll
        for (int r = 0; r < 4; ++r) {
            float ev[4];
#pragma unroll
            for (int cc = 0; cc < 4; ++cc)
                ev[cc] = e[r][cc] * QSCALE + lms[(tx << 2) + cc];
            float tmax = fmaxf(fmaxf(ev[0], ev[1]), fmaxf(ev[2], ev[3]));
#pragma unroll
            for (int d = 1; d <= 8; d <<= 1)
                tmax = fmaxf(tmax, __shfl_xor(tmax, d));
            float nm = fmaxf(mrow[r], tmax);
            float ps = 0.0f;
#pragma unroll
            for (int cc = 0; cc < 4; ++cc) ps += __expf(ev[cc] - nm);
#pragma unroll
            for (int d = 1; d <= 8; d <<= 1) ps += __shfl_xor(ps, d);
            srow[r] = srow[r] * __expf(mrow[r] - nm) + ps;
            mrow[r] = nm;
        }
    }

    float inv[4];
#pragma unroll
    for (int r = 0; r < 4; ++r) inv[r] = 1.0f / srow[r];

    float o[4][4];
#pragma unroll
    for (int r = 0; r < 4; ++r)
#pragma unroll
        for (int cc = 0; cc < 4; ++cc) o[r][cc] = 0.0f;

    // ================= Phase B: normalize, write attn_t, PV =================
    for (int lk0 = 0; lk0 < LLEN; lk0 += TK) {
        __syncthreads();   // previous iteration's LDS reads complete
        for (int idx = tid; idx < CCH * TK; idx += NTHREADS) {
            int c = idx >> 6, j = idx & 63;
            size_t g = ((size_t)(b * CCH + c)) * LLEN + lk0 + j;
            ks[c * LDP + j] = kg[g];
            vs[j * LDP + c] = vg[g];   // transposed stage
        }
        if (tid < TK) {
            float mv = maskg[(size_t)b * LLEN + lk0 + tid];
            lms[tid] = __logf(mv + 1e-6f);
            mvs[tid] = mv;
        }
        __syncthreads();

        float e[4][4];
#pragma unroll
        for (int r = 0; r < 4; ++r)
#pragma unroll
            for (int cc = 0; cc < 4; ++cc) e[r][cc] = 0.0f;

        for (int c = 0; c < CCH; ++c) {
            float4 a4 = *(const float4*)&qs[c * LDP + (ty << 2)];
            float4 b4 = *(const float4*)&ks[c * LDP + (tx << 2)];
            float av[4] = {a4.x, a4.y, a4.z, a4.w};
            float bv[4] = {b4.x, b4.y, b4.z, b4.w};
#pragma unroll
            for (int r = 0; r < 4; ++r)
#pragma unroll
                for (int cc = 0; cc < 4; ++cc) e[r][cc] += av[r] * bv[cc];
        }

        __syncthreads();   // all ks reads done; reuse ks as at[lk][lq]
#pragma unroll
        for (int r = 0; r < 4; ++r) {
#pragma unroll
            for (int cc = 0; cc < 4; ++cc) {
                int j = (tx << 2) + cc;
                float a = __expf(e[r][cc] * QSCALE + lms[j] - mrow[r]) * inv[r] * mvs[j];
                ks[j * LDP + (ty << 2) + r] = a;
            }
        }
        __syncthreads();

        // PV accumulate: o[cc][qq] = out[c=tx*4+cc][lq=ty*4+qq]
        for (int j = 0; j < TK; ++j) {
            float4 a4 = *(const float4*)&ks[j * LDP + (ty << 2)];  // attn[lq 4] (broadcast)
            float4 v4 = *(const float4*)&vs[j * LDP + (tx << 2)];  // v[c 4]
            float av[4] = {a4.x, a4.y, a4.z, a4.w};
            float vv[4] = {v4.x, v4.y, v4.z, v4.w};
#pragma unroll
            for (int cc = 0; cc < 4; ++cc)
#pragma unroll
                for (int qq = 0; qq < 4; ++qq) o[cc][qq] += vv[cc] * av[qq];
        }

        // coalesced transposed write: attn_t[b][lk][lq]
        for (int idx = tid; idx < TK * TQ; idx += NTHREADS) {
            int j = idx >> 6, i = idx & 63;
            attnT[((size_t)b * LLEN + lk0 + j) * LLEN + lq0 + i] = ks[j * LDP + i];
        }
    }

    // ---- write out[b][c][lq] ----
#pragma unroll
    for (int cc = 0; cc < 4; ++cc) {
#pragma unroll
        for (int qq = 0; qq < 4; ++qq) {
            outp[((size_t)(b * CCH + (tx << 2) + cc)) * LLEN + lq0 + (ty << 2) + qq] =
                o[cc][qq];
        }
    }
}

extern "C" void kernel_launch(void* const* d_in, const int* in_sizes, int n_in,
                              void* d_out, int out_size, void* d_ws, size_t ws_size,
                              hipStream_t stream) {
    const float* qg = (const float*)d_in[0];
    const float* kg = (const float*)d_in[1];
    const float* vg = (const float*)d_in[2];
    const float* mg = (const float*)d_in[3];
    float* outp  = (float*)d_out;
    float* attnT = outp + (size_t)BB * CCH * LLEN;

    dim3 grid(BB * (LLEN / TQ));
    dim3 block(NTHREADS);
    attn_fused<<<grid, block, 0, stream>>>(qg, kg, vg, mg, outp, attnT);
}

// Round 2
// 158.683 us; speedup vs baseline: 4.3201x; 4.3201x over previous
//
#include <hip/hip_runtime.h>

#define BB 4
#define CCH 64
#define LLEN 4096
#define QSCALE 0.125f
#define NT 512
#define TQ 64
#define TK 64
#define NTILES (LLEN / TK)
#define TPT (NTILES / 2)   // tiles per team

typedef __bf16 bf16;
typedef bf16 bf16x4 __attribute__((ext_vector_type(4)));
typedef bf16 bf16x8 __attribute__((ext_vector_type(8)));
typedef float f32x4 __attribute__((ext_vector_type(4)));

// swizzled element index into a [64 rows][64 cols] bf16 tile (128B rows):
// XOR 16B-granule (8 elems) with row&7 — breaks same-bank columns.
__device__ __forceinline__ int swz(int row, int col) {
    return row * 64 + (col ^ ((row & 7) << 3));
}

__global__ __launch_bounds__(NT) void attn_mfma(
    const float* __restrict__ qg, const float* __restrict__ kg,
    const float* __restrict__ vg, const float* __restrict__ maskg,
    float* __restrict__ outp, float* __restrict__ attnT)
{
    __shared__ __align__(16) bf16 qs[TQ * CCH];        // [lq][c] swz
    __shared__ __align__(16) bf16 ks[2][TK * CCH];     // [lk][c] swz, per team
    __shared__ __align__(16) bf16 vs[2][CCH * TK];     // [c][lk] swz, per team
    __shared__ float lms[2][TK];
    __shared__ float mvs[2][TK];
    __shared__ float smax[2][TQ];
    __shared__ float ssum[2][TQ];
    __shared__ float outbuf[CCH][TQ + 4];

    const int tid = threadIdx.x;
    const int l = tid & 63;
    const int w = tid >> 6;          // wave 0..7
    const int h = tid >> 8;          // team 0/1
    const int strip = (w & 3) * 16;  // lq strip within block tile
    const int t2 = tid & 255;        // team-local tid
    const int g = l >> 4;
    const int cl = l & 15;

    const int b = blockIdx.x / (LLEN / TQ);
    const int lq0 = (blockIdx.x % (LLEN / TQ)) * TQ;
    const size_t qkvbase = (size_t)b * CCH * LLEN;

    // ---- stage Q^T: qs[lq][c] (coalesced float2 along lq) ----
    {
        int q2 = (tid & 31) * 2;
        int c0 = tid >> 5;  // 0..15
#pragma unroll
        for (int cp = 0; cp < 4; ++cp) {
            int c = c0 + cp * 16;
            const float2 f = *(const float2*)&qg[qkvbase + (size_t)c * LLEN + lq0 + q2];
            qs[swz(q2, c)] = (bf16)f.x;
            qs[swz(q2 + 1, c)] = (bf16)f.y;
        }
    }
    __syncthreads();

    // Q fragments (B operand): elem j of k-tile s = Q[c = 32s+8g+j][lq = strip+cl]
    bf16x8 qf[2];
    qf[0] = *(const bf16x8*)&qs[swz(strip + cl, 8 * g)];
    qf[1] = *(const bf16x8*)&qs[swz(strip + cl, 32 + 8 * g)];

    float m_run = -3.0e38f, s_run = 0.0f;

    // ================= Phase A: row stats =================
    for (int it = 0; it < TPT; ++it) {
        const int lk0 = (it * 2 + h) * TK;
        __syncthreads();
        {
            int q2 = (t2 & 31) * 2;
            int c0 = t2 >> 5;  // 0..7
#pragma unroll
            for (int cp = 0; cp < 8; ++cp) {
                int c = c0 + cp * 8;
                const float2 f = *(const float2*)&kg[qkvbase + (size_t)c * LLEN + lk0 + q2];
                ks[h][swz(q2, c)] = (bf16)f.x;
                ks[h][swz(q2 + 1, c)] = (bf16)f.y;
            }
            if (t2 < TK)
                lms[h][t2] = __logf(maskg[(size_t)b * LLEN + lk0 + t2] + 1e-6f);
        }
        __syncthreads();

        f32x4 e4[4];
#pragma unroll
        for (int t = 0; t < 4; ++t) e4[t] = (f32x4){0.f, 0.f, 0.f, 0.f};
#pragma unroll
        for (int s = 0; s < 2; ++s)
#pragma unroll
            for (int t = 0; t < 4; ++t) {
                bf16x8 kf = *(const bf16x8*)&ks[h][swz(16 * t + cl, 32 * s + 8 * g)];
                e4[t] = __builtin_amdgcn_mfma_f32_16x16x32_bf16(kf, qf[s], e4[t], 0, 0, 0);
            }

        float ev[4][4];
        float tmax = -3.0e38f;
#pragma unroll
        for (int t = 0; t < 4; ++t)
#pragma unroll
            for (int r = 0; r < 4; ++r) {
                ev[t][r] = e4[t][r] * QSCALE + lms[h][16 * t + 4 * g + r];
                tmax = fmaxf(tmax, ev[t][r]);
            }
        tmax = fmaxf(tmax, __shfl_xor(tmax, 16));
        tmax = fmaxf(tmax, __shfl_xor(tmax, 32));
        float m_new = fmaxf(m_run, tmax);
        float ps = 0.f;
#pragma unroll
        for (int t = 0; t < 4; ++t)
#pragma unroll
            for (int r = 0; r < 4; ++r) ps += __expf(ev[t][r] - m_new);
        ps += __shfl_xor(ps, 16);
        ps += __shfl_xor(ps, 32);
        s_run = s_run * __expf(m_run - m_new) + ps;
        m_run = m_new;
    }

    // ---- merge team stats ----
    if (g == 0) { smax[h][strip + cl] = m_run; ssum[h][strip + cl] = s_run; }
    __syncthreads();
    float m_f, inv_s;
    {
        int lqb = strip + cl;
        float m0 = smax[0][lqb], m1 = smax[1][lqb];
        float s0 = ssum[0][lqb], s1 = ssum[1][lqb];
        m_f = fmaxf(m0, m1);
        float sf = s0 * __expf(m0 - m_f) + s1 * __expf(m1 - m_f);
        inv_s = 1.0f / sf;
    }

    // ================= Phase B: normalize, write attnT, PV =================
    f32x4 o4[4];
#pragma unroll
    for (int t = 0; t < 4; ++t) o4[t] = (f32x4){0.f, 0.f, 0.f, 0.f};

    for (int it = 0; it < TPT; ++it) {
        const int lk0 = (it * 2 + h) * TK;
        __syncthreads();
        {
            int q2 = (t2 & 31) * 2;
            int c0 = t2 >> 5;
#pragma unroll
            for (int cp = 0; cp < 8; ++cp) {
                int c = c0 + cp * 8;
                const float2 f = *(const float2*)&kg[qkvbase + (size_t)c * LLEN + lk0 + q2];
                ks[h][swz(q2, c)] = (bf16)f.x;
                ks[h][swz(q2 + 1, c)] = (bf16)f.y;
            }
            int lk4 = (t2 & 15) * 4;
            int cv0 = t2 >> 4;  // 0..15
#pragma unroll
            for (int cp = 0; cp < 4; ++cp) {
                int c = cv0 + cp * 16;
                const float4 f = *(const float4*)&vg[qkvbase + (size_t)c * LLEN + lk0 + lk4];
                bf16x4 v4 = {(bf16)f.x, (bf16)f.y, (bf16)f.z, (bf16)f.w};
                *(bf16x4*)&vs[h][swz(c, lk4)] = v4;
            }
            if (t2 < TK) {
                float mv = maskg[(size_t)b * LLEN + lk0 + t2];
                lms[h][t2] = __logf(mv + 1e-6f);
                mvs[h][t2] = mv;
            }
        }
        __syncthreads();

        f32x4 e4[4];
#pragma unroll
        for (int t = 0; t < 4; ++t) e4[t] = (f32x4){0.f, 0.f, 0.f, 0.f};
#pragma unroll
        for (int s = 0; s < 2; ++s)
#pragma unroll
            for (int t = 0; t < 4; ++t) {
                bf16x8 kf = *(const bf16x8*)&ks[h][swz(16 * t + cl, 32 * s + 8 * g)];
                e4[t] = __builtin_amdgcn_mfma_f32_16x16x32_bf16(kf, qf[s], e4[t], 0, 0, 0);
            }

        float p[4][4];
#pragma unroll
        for (int t = 0; t < 4; ++t)
#pragma unroll
            for (int r = 0; r < 4; ++r) {
                int lk = 16 * t + 4 * g + r;
                float evv = e4[t][r] * QSCALE + lms[h][lk];
                p[t][r] = __expf(evv - m_f) * inv_s * mvs[h][lk];
            }

        // direct fp32 attnT write: lanes cl consecutive -> 64B segments x4 rows
#pragma unroll
        for (int t = 0; t < 4; ++t)
#pragma unroll
            for (int r = 0; r < 4; ++r) {
                int lkg = lk0 + 16 * t + 4 * g + r;
                attnT[((size_t)b * LLEN + lkg) * LLEN + lq0 + strip + cl] = p[t][r];
            }

        // PV: A = V, B = P (lane-local). sigma(g,j,s) = 32s + 16*(j>>2) + 4g + (j&3)
        bf16x8 pb[2];
#pragma unroll
        for (int s = 0; s < 2; ++s)
#pragma unroll
            for (int j = 0; j < 8; ++j)
                pb[s][j] = (bf16)p[2 * s + (j >> 2)][j & 3];
#pragma unroll
        for (int s = 0; s < 2; ++s)
#pragma unroll
            for (int mt = 0; mt < 4; ++mt) {
                int c = 16 * mt + cl;
                bf16x4 vlo = *(const bf16x4*)&vs[h][swz(c, 32 * s + 4 * g)];
                bf16x4 vhi = *(const bf16x4*)&vs[h][swz(c, 32 * s + 16 + 4 * g)];
                bf16x8 vf = __builtin_shufflevector(vlo, vhi, 0, 1, 2, 3, 4, 5, 6, 7);
                o4[mt] = __builtin_amdgcn_mfma_f32_16x16x32_bf16(vf, pb[s], o4[mt], 0, 0, 0);
            }
    }

    // ---- merge PV partials across teams, write out ----
    if (h == 1) {
#pragma unroll
        for (int mt = 0; mt < 4; ++mt)
#pragma unroll
            for (int r = 0; r < 4; ++r)
                outbuf[16 * mt + 4 * g + r][strip + cl] = o4[mt][r];
    }
    __syncthreads();
    if (h == 0) {
#pragma unroll
        for (int mt = 0; mt < 4; ++mt)
#pragma unroll
            for (int r = 0; r < 4; ++r) {
                int c = 16 * mt + 4 * g + r;
                outp[qkvbase + (size_t)c * LLEN + lq0 + strip + cl] =
                    o4[mt][r] + outbuf[c][strip + cl];
            }
    }
}

extern "C" void kernel_launch(void* const* d_in, const int* in_sizes, int n_in,
                              void* d_out, int out_size, void* d_ws, size_t ws_size,
                              hipStream_t stream) {
    const float* qg = (const float*)d_in[0];
    const float* kg = (const float*)d_in[1];
    const float* vg = (const float*)d_in[2];
    const float* mg = (const float*)d_in[3];
    float* outp = (float*)d_out;
    float* attnT = outp + (size_t)BB * CCH * LLEN;

    dim3 grid(BB * (LLEN / TQ));
    dim3 block(NT);
    attn_mfma<<<grid, block, 0, stream>>>(qg, kg, vg, mg, outp, attnT);
}